// Round 4
// baseline (4472.547 us; speedup 1.0000x reference)
//
#include <hip/hip_runtime.h>
#include <hip/hip_bf16.h>
#include <math.h>

#define D_MODEL 512
#define NHEAD 4
#define DHEAD 128
#define DFF 2048
#define NLAYER 2
#define SCTX 2048
#define PREDN 2
#define BATCH 8
#define S_TOT 2050              // SCTX + PREDN
#define M_ROWS (BATCH * S_TOT)  // 16400
#define LN_EPS 1e-5f

typedef __attribute__((ext_vector_type(8))) short bf16x8;
typedef __attribute__((ext_vector_type(4))) float f32x4;

__device__ inline ushort f2b(float f) {
  union { __hip_bfloat16 b; ushort u; } cv;
  cv.b = __float2bfloat16(f);
  return cv.u;
}
__device__ inline float b2f(ushort u) {
  union { float f; unsigned int i; } cv;
  cv.i = ((unsigned int)u) << 16;
  return cv.f;
}

// ---------------------------------------------------------------- cast
__global__ __launch_bounds__(256) void cast_f32_bf16(
    const float* __restrict__ in, ushort* __restrict__ out, int n4) {
  int i = blockIdx.x * 256 + threadIdx.x;
  if (i >= n4) return;
  float4 v = *(const float4*)&in[(long)i * 4];
  ushort4 o;
  o.x = f2b(v.x); o.y = f2b(v.y); o.z = f2b(v.z); o.w = f2b(v.w);
  *(ushort4*)&out[(long)i * 4] = o;
}

// ---------------------------------------------------------------- embedding
__global__ __launch_bounds__(256) void embed_kernel(
    const int* __restrict__ cat, const int* __restrict__ timev,
    const int* __restrict__ f0, const float* __restrict__ w_cat,
    const float* __restrict__ pad_emb, float* __restrict__ x,
    ushort* __restrict__ xb) {
  int idx = blockIdx.x * 256 + threadIdx.x;  // over M_ROWS * 512
  if (idx >= M_ROWS * D_MODEL) return;
  int d = idx & (D_MODEL - 1);
  int row = idx >> 9;
  int b = row / S_TOT;
  int s = row - b * S_TOT;
  float val;
  if (s >= SCTX) {
    val = pad_emb[d];
  } else if (d < 256) {
    int c = cat[b * SCTX + s];
    val = w_cat[(long)c * 256 + d];
  } else {
    int i = (d < 384) ? (d - 256) : (d - 384);
    int v = (d < 384) ? timev[b * SCTX + s] : f0[b * SCTX + s];
    float freq = expf(-(float)i * (9.210340371976184f / 128.0f));  // 10000^(-i/128)
    float ang = (float)v * freq;
    val = (i & 1) ? cosf(ang) : sinf(ang);
  }
  x[idx] = val;
  xb[idx] = f2b(val);
}

// ---------------------------------------------------------------- MFMA GEMM
// C[M,N] = A[M,K] @ W[N,K]^T + bias[N].  A,W bf16; accumulate f32.
// 128x128 tile, BK=32, 4 waves each owning a 64x64 sub-tile (4x4 of 16x16).
__global__ __launch_bounds__(256) void gemm_bf16(
    const ushort* __restrict__ A, const ushort* __restrict__ W,
    const float* __restrict__ bias, void* __restrict__ Cout,
    int M, int N, int K, int out_bf16, int relu) {
  // rows padded to 40 shorts (80 B): bank-group stride 5, coprime with 8
  __shared__ alignas(16) ushort As[128][40];
  __shared__ alignas(16) ushort Bs[128][40];
  int tid = threadIdx.x;
  int lane = tid & 63;
  int wv = tid >> 6;
  int wr = wv >> 1, wc = wv & 1;
  int m0 = blockIdx.y * 128, n0 = blockIdx.x * 128;
  f32x4 acc[4][4];
#pragma unroll
  for (int m = 0; m < 4; ++m)
#pragma unroll
    for (int n = 0; n < 4; ++n) acc[m][n] = (f32x4){0.f, 0.f, 0.f, 0.f};

  int r_ld = lane & 15;  // fragment row/col within 16
  int g_ld = lane >> 4;  // k-octet 0..3 (8 bf16 each)

  for (int k0 = 0; k0 < K; k0 += 32) {
#pragma unroll
    for (int i = 0; i < 2; ++i) {
      int idx = tid + i * 256;  // 0..511 slots of 8 bf16 (128 rows x 4)
      int row = idx >> 2, k8 = idx & 3;
      int ga = m0 + row; if (ga > M - 1) ga = M - 1;   // clamp: no OOB reads
      int4 av = *(const int4*)&A[(long)ga * K + k0 + k8 * 8];
      *(int4*)&As[row][k8 * 8] = av;
      int gb = n0 + row; if (gb > N - 1) gb = N - 1;
      int4 bv = *(const int4*)&W[(long)gb * K + k0 + k8 * 8];
      *(int4*)&Bs[row][k8 * 8] = bv;
    }
    __syncthreads();
    bf16x8 af[4], bfr[4];
#pragma unroll
    for (int m = 0; m < 4; ++m)
      af[m] = *(const bf16x8*)&As[wr * 64 + m * 16 + r_ld][g_ld * 8];
#pragma unroll
    for (int n = 0; n < 4; ++n)
      bfr[n] = *(const bf16x8*)&Bs[wc * 64 + n * 16 + r_ld][g_ld * 8];
#pragma unroll
    for (int m = 0; m < 4; ++m)
#pragma unroll
      for (int n = 0; n < 4; ++n)
        acc[m][n] = __builtin_amdgcn_mfma_f32_16x16x32_bf16(af[m], bfr[n],
                                                            acc[m][n], 0, 0, 0);
    __syncthreads();
  }
  // epilogue: C/D layout col=lane&15, row=(lane>>4)*4+reg  [m89/m91]
  int r4 = lane >> 4, cc = lane & 15;
#pragma unroll
  for (int m = 0; m < 4; ++m) {
#pragma unroll
    for (int n = 0; n < 4; ++n) {
      int gn = n0 + wc * 64 + n * 16 + cc;
      float bv = bias[gn];
#pragma unroll
      for (int reg = 0; reg < 4; ++reg) {
        int gm = m0 + wr * 64 + m * 16 + r4 * 4 + reg;
        if (gm >= M) continue;
        float v = acc[m][n][reg] + bv;
        if (relu) v = fmaxf(v, 0.f);
        if (out_bf16)
          ((ushort*)Cout)[(long)gm * N + gn] = f2b(v);
        else
          ((float*)Cout)[(long)gm * N + gn] = v;
      }
    }
  }
}

// ---------------------------------------------------------------- attention
// One block per (q-tile of 32, head, batch). f32 flash with 32-key tiles.
// qkv is bf16 [M_ROWS][1536]; output bf16.
__global__ __launch_bounds__(256) void attn_kernel(
    const ushort* __restrict__ qkv, ushort* __restrict__ attb) {
  int qt = blockIdx.x, h = blockIdx.y, b = blockIdx.z;
  int q0 = qt * 32;
  __shared__ alignas(16) float Qs[32][132];
  __shared__ alignas(16) float Ks[32][132];
  __shared__ alignas(16) float Vs[32][132];
  __shared__ float Ss[32][33];
  __shared__ float mrow[32], lrow[32], cfrow[32];
  int tid = threadIdx.x;
#pragma unroll
  for (int r = 0; r < 4; ++r) {
    int e = tid + r * 256;  // over 32 rows x 32 chunks of 4
    int q = e >> 5, d4 = e & 31;
    int gq = q0 + q;
    float4 v = make_float4(0.f, 0.f, 0.f, 0.f);
    if (gq < S_TOT) {
      ushort4 u = *(const ushort4*)&qkv[((long)(b * S_TOT + gq)) * 1536 +
                                        h * 128 + d4 * 4];
      v = make_float4(b2f(u.x), b2f(u.y), b2f(u.z), b2f(u.w));
    }
    *(float4*)&Qs[q][d4 * 4] = v;
  }
  if (tid < 32) { mrow[tid] = -1e30f; lrow[tid] = 0.f; }
  float oacc[16] = {};
  int qown = tid >> 3;
  int dbase = (tid & 7) * 16;
  int ktmax = min(qt, 63);  // keys allowed: k <= min(q, 2047)
  __syncthreads();
  for (int kt = 0; kt <= ktmax; ++kt) {
    int k0 = kt * 32;
#pragma unroll
    for (int r = 0; r < 4; ++r) {
      int e = tid + r * 256;
      int k = e >> 5, d4 = e & 31;
      long base = ((long)(b * S_TOT + k0 + k)) * 1536 + 512 + h * 128;
      ushort4 ku = *(const ushort4*)&qkv[base + d4 * 4];
      ushort4 vu = *(const ushort4*)&qkv[base + 512 + d4 * 4];
      *(float4*)&Ks[k][d4 * 4] =
          make_float4(b2f(ku.x), b2f(ku.y), b2f(ku.z), b2f(ku.w));
      *(float4*)&Vs[k][d4 * 4] =
          make_float4(b2f(vu.x), b2f(vu.y), b2f(vu.z), b2f(vu.w));
    }
    __syncthreads();
    float sv[4];
#pragma unroll
    for (int e = 0; e < 4; ++e) {
      int idx = tid + e * 256;
      int q = idx >> 5, k = idx & 31;
      float sum = 0.f;
#pragma unroll 8
      for (int d4 = 0; d4 < 32; ++d4) {
        float4 qv = *(const float4*)&Qs[q][d4 * 4];
        float4 kv = *(const float4*)&Ks[k][d4 * 4];
        sum += qv.x * kv.x + qv.y * kv.y + qv.z * kv.z + qv.w * kv.w;
      }
      sum *= 0.08838834764831845f;  // 1/sqrt(128)
      int gq = q0 + q, gk = k0 + k;
      if (gk > gq || gk > (SCTX - 1) || gq >= S_TOT) sum = -1e9f;
      sv[e] = sum;
    }
#pragma unroll
    for (int e = 0; e < 4; ++e) {
      int idx = tid + e * 256;
      Ss[idx >> 5][idx & 31] = sv[e];
    }
    __syncthreads();
    if (tid < 32) {
      float mo = mrow[tid];
      float mt = mo;
#pragma unroll
      for (int k = 0; k < 32; ++k) mt = fmaxf(mt, Ss[tid][k]);
      float cf = expf(mo - mt);
      float ls = 0.f;
#pragma unroll
      for (int k = 0; k < 32; ++k) {
        float p = expf(Ss[tid][k] - mt);
        Ss[tid][k] = p;
        ls += p;
      }
      lrow[tid] = lrow[tid] * cf + ls;
      mrow[tid] = mt;
      cfrow[tid] = cf;
    }
    __syncthreads();
    float cf = cfrow[qown];
#pragma unroll
    for (int j = 0; j < 16; ++j) oacc[j] *= cf;
    for (int k = 0; k < 32; ++k) {
      float p = Ss[qown][k];
      const float* vrow = &Vs[k][dbase];
#pragma unroll
      for (int j4 = 0; j4 < 4; ++j4) {
        float4 vv = *(const float4*)&vrow[j4 * 4];
        oacc[j4 * 4 + 0] += p * vv.x;
        oacc[j4 * 4 + 1] += p * vv.y;
        oacc[j4 * 4 + 2] += p * vv.z;
        oacc[j4 * 4 + 3] += p * vv.w;
      }
    }
    __syncthreads();
  }
  int gq = q0 + qown;
  if (gq < S_TOT) {
    float inv = 1.0f / lrow[qown];
    ushort* orow = &attb[((long)(b * S_TOT + gq)) * 512 + h * 128 + dbase];
#pragma unroll
    for (int j = 0; j < 16; ++j) orow[j] = f2b(oacc[j] * inv);
  }
}

// ---------------------------------------------------------------- layernorm
// x[row] = LN(x[row] + add[row]) * g + b (in-place on x) + bf16 copy.
__global__ __launch_bounds__(256) void ln_kernel(
    float* __restrict__ x, const float* __restrict__ add,
    const float* __restrict__ g, const float* __restrict__ bta,
    ushort* __restrict__ xb) {
  int row = blockIdx.x;
  int tid = threadIdx.x;
  long base = (long)row * 512;
  float v0 = x[base + tid] + add[base + tid];
  float v1 = x[base + 256 + tid] + add[base + 256 + tid];
  float s = v0 + v1;
  float s2 = v0 * v0 + v1 * v1;
  __shared__ float red[8];
#pragma unroll
  for (int o = 32; o > 0; o >>= 1) {
    s += __shfl_down(s, o);
    s2 += __shfl_down(s2, o);
  }
  int wid = tid >> 6;
  if ((tid & 63) == 0) { red[wid] = s; red[4 + wid] = s2; }
  __syncthreads();
  float ts = red[0] + red[1] + red[2] + red[3];
  float ts2 = red[4] + red[5] + red[6] + red[7];
  float mean = ts * (1.f / 512.f);
  float var = ts2 * (1.f / 512.f) - mean * mean;
  float inv = 1.0f / sqrtf(var + LN_EPS);
  float o0 = (v0 - mean) * inv * g[tid] + bta[tid];
  float o1 = (v1 - mean) * inv * g[256 + tid] + bta[256 + tid];
  x[base + tid] = o0;
  x[base + 256 + tid] = o1;
  xb[base + tid] = f2b(o0);
  xb[base + 256 + tid] = f2b(o1);
}

// ---------------------------------------------------------------- heads
__global__ __launch_bounds__(256) void head_cat_kernel(
    const float* __restrict__ x, const float* __restrict__ w_cat,
    float* __restrict__ out0) {
  __shared__ alignas(16) float Pc[16][260];
  __shared__ alignas(16) float Ws[16][260];
  int tid = threadIdx.x;
#pragma unroll
  for (int r = 0; r < 4; ++r) {
    int e = tid + r * 256;  // float4 idx over 16*64
    int rr = e >> 6, d4 = e & 63;
    int b = rr >> 1, p = rr & 1;
    *(float4*)&Pc[rr][d4 * 4] =
        *(const float4*)&x[((long)(b * S_TOT + SCTX + p)) * 512 + d4 * 4];
  }
  int n0 = blockIdx.x * 256;
  for (int nc = 0; nc < 256; nc += 16) {
    __syncthreads();
#pragma unroll
    for (int r = 0; r < 4; ++r) {
      int e = tid + r * 256;
      int rr = e >> 6, d4 = e & 63;
      int n = n0 + nc + rr;
      float4 w = make_float4(0.f, 0.f, 0.f, 0.f);
      if (n < 50000) w = *(const float4*)&w_cat[(long)n * 256 + d4 * 4];
      *(float4*)&Ws[rr][d4 * 4] = w;
    }
    __syncthreads();
    int rr = tid >> 4, nn = tid & 15;
    float sum = 0.f;
#pragma unroll 8
    for (int d4 = 0; d4 < 64; ++d4) {
      float4 a = *(const float4*)&Pc[rr][d4 * 4];
      float4 w = *(const float4*)&Ws[nn][d4 * 4];
      sum += a.x * w.x + a.y * w.y + a.z * w.z + a.w * w.w;
    }
    int n = n0 + nc + nn;
    int b = rr >> 1, p = rr & 1;
    if (n < 50000) out0[((long)(b * 2 + p)) * 50000 + n] = sum;
  }
}

__global__ __launch_bounds__(256) void head_cont_kernel(
    const float* __restrict__ x, float* __restrict__ out1,
    float* __restrict__ out2) {
  __shared__ alignas(16) float Pt[16][132];
  __shared__ alignas(16) float Pf[16][132];
  __shared__ alignas(16) float Ws[16][132];
  int tid = threadIdx.x;
#pragma unroll
  for (int r = 0; r < 2; ++r) {
    int e = tid + r * 256;  // float4 idx over 16*32
    int rr = e >> 5, d4 = e & 31;
    int b = rr >> 1, p = rr & 1;
    long base = ((long)(b * S_TOT + SCTX + p)) * 512;
    *(float4*)&Pt[rr][d4 * 4] = *(const float4*)&x[base + 256 + d4 * 4];
    *(float4*)&Pf[rr][d4 * 4] = *(const float4*)&x[base + 384 + d4 * 4];
  }
  int n0 = blockIdx.x * 256;
  for (int nc = 0; nc < 256; nc += 16) {
    __syncthreads();
#pragma unroll
    for (int r = 0; r < 8; ++r) {
      int e = tid + r * 256;  // over 16 rows x 128 i
      int rr = e >> 7, i = e & 127;
      int n = n0 + nc + rr;
      float freq = expf(-(float)i * (6.907755278982137f / 128.f));  // 1000^(-i/128)
      float ang = (float)n * freq;
      Ws[rr][i] = (i & 1) ? cosf(ang) : sinf(ang);
    }
    __syncthreads();
    int rr = tid >> 4, nn = tid & 15;
    float s1 = 0.f, s2 = 0.f;
#pragma unroll 8
    for (int d4 = 0; d4 < 32; ++d4) {
      float4 w = *(const float4*)&Ws[nn][d4 * 4];
      float4 a = *(const float4*)&Pt[rr][d4 * 4];
      float4 c = *(const float4*)&Pf[rr][d4 * 4];
      s1 += a.x * w.x + a.y * w.y + a.z * w.z + a.w * w.w;
      s2 += c.x * w.x + c.y * w.y + c.z * w.z + c.w * w.w;
    }
    int n = n0 + nc + nn;
    int b = rr >> 1, p = rr & 1;
    out1[((long)(b * 2 + p)) * 4096 + n] = s1;
    out2[((long)(b * 2 + p)) * 4096 + n] = s2;
  }
}

// ---------------------------------------------------------------- launch
extern "C" void kernel_launch(void* const* d_in, const int* in_sizes, int n_in,
                              void* d_out, int out_size, void* d_ws,
                              size_t ws_size, hipStream_t stream) {
  const int* cat = (const int*)d_in[0];
  const int* timev = (const int*)d_in[1];
  const int* f0 = (const int*)d_in[2];
  const float* w_cat = (const float*)d_in[3];
  const float* pad_emb = (const float*)d_in[4];
  const float* attn_in_w = (const float*)d_in[5];
  const float* attn_in_b = (const float*)d_in[6];
  const float* attn_out_w = (const float*)d_in[7];
  const float* attn_out_b = (const float*)d_in[8];
  const float* ff1_w = (const float*)d_in[9];
  const float* ff1_b = (const float*)d_in[10];
  const float* ff2_w = (const float*)d_in[11];
  const float* ff2_b = (const float*)d_in[12];
  const float* ln1_g = (const float*)d_in[13];
  const float* ln1_b = (const float*)d_in[14];
  const float* ln2_g = (const float*)d_in[15];
  const float* ln2_b = (const float*)d_in[16];

  // -------- workspace layout: 180.5 MB total --------
  // X(f32 33.6M) TMP(f32 33.6M) Xb(16.8M) ATTb(16.8M) U(67.2M) Wb(12.6M)
  const size_t REQUIRED = 180518912ull;
  if (ws_size < REQUIRED) return;  // clean fail (poisoned out), never a crash

  float* X = (float*)d_ws;                            // 16400*512 f32
  float* TMP = X + (long)M_ROWS * 512;                // 16400*512 f32
  ushort* Xb = (ushort*)(TMP + (long)M_ROWS * 512);   // 16400*512 bf16
  ushort* ATTb = Xb + (long)M_ROWS * 512;             // 16400*512 bf16
  ushort* U = ATTb + (long)M_ROWS * 512;              // union: QKV(16400*1536) / HMID(16400*2048)
  ushort* Wb_ain = U + (long)M_ROWS * 2048;           // 2*1536*512
  ushort* Wb_aout = Wb_ain + 2 * 1536 * 512;          // 2*512*512
  ushort* Wb_ff1 = Wb_aout + 2 * 512 * 512;           // 2*2048*512
  ushort* Wb_ff2 = Wb_ff1 + 2 * 2048 * 512;           // 2*512*2048

  float* out0 = (float*)d_out;  // 8*2*50000
  float* out1 = out0 + 800000;  // 8*2*4096
  float* out2 = out1 + 65536;   // 8*2*4096

  // -------- weight casts (once per launch) --------
  cast_f32_bf16<<<1536, 256, 0, stream>>>(attn_in_w, Wb_ain, 2 * 1536 * 512 / 4);
  cast_f32_bf16<<<512, 256, 0, stream>>>(attn_out_w, Wb_aout, 2 * 512 * 512 / 4);
  cast_f32_bf16<<<2048, 256, 0, stream>>>(ff1_w, Wb_ff1, 2 * 2048 * 512 / 4);
  cast_f32_bf16<<<2048, 256, 0, stream>>>(ff2_w, Wb_ff2, 2 * 512 * 2048 / 4);

  embed_kernel<<<(M_ROWS * 512) / 256, 256, 0, stream>>>(cat, timev, f0, w_cat,
                                                         pad_emb, X, Xb);
  int mtiles = (M_ROWS + 127) / 128;  // 129
  for (int l = 0; l < NLAYER; ++l) {
    gemm_bf16<<<dim3(12, mtiles), 256, 0, stream>>>(
        Xb, Wb_ain + (long)l * 1536 * 512, attn_in_b + l * 1536, U, M_ROWS,
        1536, 512, 1, 0);  // QKV -> bf16 in U
    attn_kernel<<<dim3(65, NHEAD, BATCH), 256, 0, stream>>>(U, ATTb);
    gemm_bf16<<<dim3(4, mtiles), 256, 0, stream>>>(
        ATTb, Wb_aout + (long)l * 512 * 512, attn_out_b + l * 512, TMP, M_ROWS,
        512, 512, 0, 0);
    ln_kernel<<<M_ROWS, 256, 0, stream>>>(X, TMP, ln1_g + l * 512,
                                          ln1_b + l * 512, Xb);
    gemm_bf16<<<dim3(16, mtiles), 256, 0, stream>>>(
        Xb, Wb_ff1 + (long)l * 2048 * 512, ff1_b + l * 2048, U, M_ROWS, 2048,
        512, 1, 1);  // HMID -> bf16 relu in U
    gemm_bf16<<<dim3(4, mtiles), 256, 0, stream>>>(
        U, Wb_ff2 + (long)l * 512 * 2048, ff2_b + l * 512, TMP, M_ROWS, 512,
        2048, 0, 0);
    ln_kernel<<<M_ROWS, 256, 0, stream>>>(X, TMP, ln2_g + l * 512,
                                          ln2_b + l * 512, Xb);
  }
  head_cat_kernel<<<196, 256, 0, stream>>>(X, w_cat, out0);
  head_cont_kernel<<<16, 256, 0, stream>>>(X, out1, out2);
}

// Round 5
// 1401.393 us; speedup vs baseline: 3.1915x; 3.1915x over previous
//
#include <hip/hip_runtime.h>
#include <hip/hip_bf16.h>
#include <math.h>

#define D_MODEL 512
#define NHEAD 4
#define DHEAD 128
#define DFF 2048
#define NLAYER 2
#define SCTX 2048
#define PREDN 2
#define BATCH 8
#define S_TOT 2050              // SCTX + PREDN
#define M_ROWS (BATCH * S_TOT)  // 16400
#define LN_EPS 1e-5f
#define SCALE 0.08838834764831845f

typedef __attribute__((ext_vector_type(8))) short bf16x8;
typedef __attribute__((ext_vector_type(4))) float f32x4;

__device__ inline ushort f2b(float f) {
  union { __hip_bfloat16 b; ushort u; } cv;
  cv.b = __float2bfloat16(f);
  return cv.u;
}
__device__ inline float b2f(ushort u) {
  union { float f; unsigned int i; } cv;
  cv.i = ((unsigned int)u) << 16;
  return cv.f;
}

// ---------------------------------------------------------------- cast
__global__ __launch_bounds__(256) void cast_f32_bf16(
    const float* __restrict__ in, ushort* __restrict__ out, int n4) {
  int i = blockIdx.x * 256 + threadIdx.x;
  if (i >= n4) return;
  float4 v = *(const float4*)&in[(long)i * 4];
  ushort4 o;
  o.x = f2b(v.x); o.y = f2b(v.y); o.z = f2b(v.z); o.w = f2b(v.w);
  *(ushort4*)&out[(long)i * 4] = o;
}

// ---------------------------------------------------------------- embedding
__global__ __launch_bounds__(256) void embed_kernel(
    const int* __restrict__ cat, const int* __restrict__ timev,
    const int* __restrict__ f0, const float* __restrict__ w_cat,
    const float* __restrict__ pad_emb, float* __restrict__ x,
    ushort* __restrict__ xb) {
  int idx = blockIdx.x * 256 + threadIdx.x;  // over M_ROWS * 512
  if (idx >= M_ROWS * D_MODEL) return;
  int d = idx & (D_MODEL - 1);
  int row = idx >> 9;
  int b = row / S_TOT;
  int s = row - b * S_TOT;
  float val;
  if (s >= SCTX) {
    val = pad_emb[d];
  } else if (d < 256) {
    int c = cat[b * SCTX + s];
    val = w_cat[(long)c * 256 + d];
  } else {
    int i = (d < 384) ? (d - 256) : (d - 384);
    int v = (d < 384) ? timev[b * SCTX + s] : f0[b * SCTX + s];
    float freq = expf(-(float)i * (9.210340371976184f / 128.0f));  // 10000^(-i/128)
    float ang = (float)v * freq;
    val = (i & 1) ? cosf(ang) : sinf(ang);
  }
  x[idx] = val;
  xb[idx] = f2b(val);
}

// ---------------------------------------------------------------- MFMA GEMM
// C[M,N] = A[M,K] @ W[N,K]^T + bias[N].  A,W bf16; accumulate f32.
__global__ __launch_bounds__(256) void gemm_bf16(
    const ushort* __restrict__ A, const ushort* __restrict__ W,
    const float* __restrict__ bias, void* __restrict__ Cout,
    int M, int N, int K, int out_bf16, int relu) {
  __shared__ alignas(16) ushort As[128][40];
  __shared__ alignas(16) ushort Bs[128][40];
  int tid = threadIdx.x;
  int lane = tid & 63;
  int wv = tid >> 6;
  int wr = wv >> 1, wc = wv & 1;
  int m0 = blockIdx.y * 128, n0 = blockIdx.x * 128;
  f32x4 acc[4][4];
#pragma unroll
  for (int m = 0; m < 4; ++m)
#pragma unroll
    for (int n = 0; n < 4; ++n) acc[m][n] = (f32x4){0.f, 0.f, 0.f, 0.f};

  int r_ld = lane & 15;
  int g_ld = lane >> 4;

  for (int k0 = 0; k0 < K; k0 += 32) {
#pragma unroll
    for (int i = 0; i < 2; ++i) {
      int idx = tid + i * 256;
      int row = idx >> 2, k8 = idx & 3;
      int ga = m0 + row; if (ga > M - 1) ga = M - 1;
      int4 av = *(const int4*)&A[(long)ga * K + k0 + k8 * 8];
      *(int4*)&As[row][k8 * 8] = av;
      int gb = n0 + row; if (gb > N - 1) gb = N - 1;
      int4 bv = *(const int4*)&W[(long)gb * K + k0 + k8 * 8];
      *(int4*)&Bs[row][k8 * 8] = bv;
    }
    __syncthreads();
    bf16x8 af[4], bfr[4];
#pragma unroll
    for (int m = 0; m < 4; ++m)
      af[m] = *(const bf16x8*)&As[wr * 64 + m * 16 + r_ld][g_ld * 8];
#pragma unroll
    for (int n = 0; n < 4; ++n)
      bfr[n] = *(const bf16x8*)&Bs[wc * 64 + n * 16 + r_ld][g_ld * 8];
#pragma unroll
    for (int m = 0; m < 4; ++m)
#pragma unroll
      for (int n = 0; n < 4; ++n)
        acc[m][n] = __builtin_amdgcn_mfma_f32_16x16x32_bf16(af[m], bfr[n],
                                                            acc[m][n], 0, 0, 0);
    __syncthreads();
  }
  int r4 = lane >> 4, cc = lane & 15;
#pragma unroll
  for (int m = 0; m < 4; ++m) {
#pragma unroll
    for (int n = 0; n < 4; ++n) {
      int gn = n0 + wc * 64 + n * 16 + cc;
      float bv = bias[gn];
#pragma unroll
      for (int reg = 0; reg < 4; ++reg) {
        int gm = m0 + wr * 64 + m * 16 + r4 * 4 + reg;
        if (gm >= M) continue;
        float v = acc[m][n][reg] + bv;
        if (relu) v = fmaxf(v, 0.f);
        if (out_bf16)
          ((ushort*)Cout)[(long)gm * N + gn] = f2b(v);
        else
          ((float*)Cout)[(long)gm * N + gn] = v;
      }
    }
  }
}

// ---------------------------------------------------------------- V transpose
// Vt[(b*4+h)*128 + d][s] = V[b, s, h, d]  for s in [0, 2048)
__global__ __launch_bounds__(256) void vt_kernel(
    const ushort* __restrict__ qkv, ushort* __restrict__ vt) {
  int idx = blockIdx.x * 256 + threadIdx.x;  // 0 .. 1048575
  int s8 = idx & 255;
  int rbh = idx >> 8;  // 0..4095 = (b*4+h)*128 + d
  int d = rbh & 127;
  int bh = rbh >> 7;
  int h = bh & 3, b = bh >> 2;
  int s0 = s8 * 8;
  long src = (long)(b * S_TOT + s0) * 1536 + 1024 + h * 128 + d;
  ushort4 t0, t1;
  t0.x = qkv[src];
  t0.y = qkv[src + 1536];
  t0.z = qkv[src + 3072];
  t0.w = qkv[src + 4608];
  t1.x = qkv[src + 6144];
  t1.y = qkv[src + 7680];
  t1.z = qkv[src + 9216];
  t1.w = qkv[src + 10752];
  ushort* dst = &vt[(long)rbh * 2048 + s0];
  *(ushort4*)dst = t0;
  *(ushort4*)(dst + 4) = t1;
}

// ---------------------------------------------------------------- attention
// MFMA flash attention. Block = 64 q rows (4 waves x 16), KV tiles of 32.
// qkv bf16 [M_ROWS][1536]; vt bf16 [(b*4+h)*128+d][2048]; out bf16.
__global__ __launch_bounds__(256) void attn_mfma(
    const ushort* __restrict__ qkv, const ushort* __restrict__ vt,
    ushort* __restrict__ attb) {
  int qt = blockIdx.x, h = blockIdx.y, b = blockIdx.z;
  int q0 = qt * 64;
  int tid = threadIdx.x;
  int lane = tid & 63;
  int w = tid >> 6;
  int qbase = q0 + w * 16;

  __shared__ alignas(16) ushort Ks[32][128];    // 8 KB
  __shared__ alignas(16) ushort Vts[128][32];   // 8 KB
  __shared__ alignas(16) ushort Ps[4][16][40];  // 5 KB

  // Q fragments: A[row=q=lane&15][k=d=(lane>>4)*8 + ks*32]
  bf16x8 qf[4];
  {
    int gq = qbase + (lane & 15);
    if (gq > S_TOT - 1) gq = S_TOT - 1;
    const ushort* qrow =
        &qkv[(long)(b * S_TOT + gq) * 1536 + h * 128 + (lane >> 4) * 8];
#pragma unroll
    for (int ks = 0; ks < 4; ++ks) qf[ks] = *(const bf16x8*)&qrow[ks * 32];
  }

  f32x4 of[8];
#pragma unroll
  for (int df = 0; df < 8; ++df) of[df] = (f32x4){0.f, 0.f, 0.f, 0.f};
  float m_r[4] = {-3e38f, -3e38f, -3e38f, -3e38f};
  float l_r[4] = {0.f, 0.f, 0.f, 0.f};

  int kmax_blk = min(q0 + 63, SCTX - 1);
  int ktn = (kmax_blk >> 5) + 1;
  int wave_qmax = qbase + 15;

  for (int kt = 0; kt < ktn; ++kt) {
    int k0 = kt * 32;
    __syncthreads();  // protect LDS from previous iteration's readers
    // stage K tile (32 rows x 128 d)
#pragma unroll
    for (int r = 0; r < 2; ++r) {
      int idx = tid + r * 256;
      int row = idx >> 4, c8 = idx & 15;
      long g = (long)(b * S_TOT + k0 + row) * 1536 + 512 + h * 128 + c8 * 8;
      *(int4*)&Ks[row][c8 * 8] = *(const int4*)&qkv[g];
    }
    // stage Vt tile (128 d-rows x 32 keys)
#pragma unroll
    for (int r = 0; r < 2; ++r) {
      int idx = tid + r * 256;
      int row = idx >> 2, c8 = idx & 3;
      long g = ((long)((b * NHEAD + h) * 128 + row)) * 2048 + k0 + c8 * 8;
      *(int4*)&Vts[row][c8 * 8] = *(const int4*)&vt[g];
    }
    __syncthreads();

    bool active = (k0 <= wave_qmax);
    if (active) {
      // QK^T: D[q][key], q=(lane>>4)*4+reg (A-side), key=(lane&15)+16*nf
      f32x4 sf0 = (f32x4){0.f, 0.f, 0.f, 0.f};
      f32x4 sf1 = (f32x4){0.f, 0.f, 0.f, 0.f};
#pragma unroll
      for (int ks = 0; ks < 4; ++ks) {
        bf16x8 kf0 = *(const bf16x8*)&Ks[lane & 15][(lane >> 4) * 8 + ks * 32];
        bf16x8 kf1 =
            *(const bf16x8*)&Ks[16 + (lane & 15)][(lane >> 4) * 8 + ks * 32];
        sf0 = __builtin_amdgcn_mfma_f32_16x16x32_bf16(qf[ks], kf0, sf0, 0, 0, 0);
        sf1 = __builtin_amdgcn_mfma_f32_16x16x32_bf16(qf[ks], kf1, sf1, 0, 0, 0);
      }
      int kbase = k0 + (lane & 15);
#pragma unroll
      for (int reg = 0; reg < 4; ++reg) {
        int ql = (lane >> 4) * 4 + reg;
        int gq = qbase + ql;
        bool v0 = (kbase <= gq) && (kbase <= SCTX - 1);
        bool v1 = (kbase + 16 <= gq) && (kbase + 16 <= SCTX - 1);
        float s0 = sf0[reg] * SCALE;
        float s1 = sf1[reg] * SCALE;
        float mx = fmaxf(v0 ? s0 : -3e38f, v1 ? s1 : -3e38f);
#pragma unroll
        for (int off = 1; off < 16; off <<= 1)
          mx = fmaxf(mx, __shfl_xor(mx, off));
        float mo = m_r[reg];
        float mn = fmaxf(mo, mx);
        float cf = __expf(mo - mn);
        float p0 = v0 ? __expf(s0 - mn) : 0.f;
        float p1 = v1 ? __expf(s1 - mn) : 0.f;
        float rs = p0 + p1;
#pragma unroll
        for (int off = 1; off < 16; off <<= 1) rs += __shfl_xor(rs, off);
        l_r[reg] = l_r[reg] * cf + rs;
        m_r[reg] = mn;
#pragma unroll
        for (int df = 0; df < 8; ++df) of[df][reg] *= cf;
        Ps[w][ql][lane & 15] = f2b(p0);
        Ps[w][ql][16 + (lane & 15)] = f2b(p1);
      }
    }
    __syncthreads();  // P visible (and uniform across waves)
    if (active) {
      // PV: A=P[q=lane&15][key=(lane>>4)*8+j], B=Vt[d][key] -> D[q][d]
      bf16x8 pa = *(const bf16x8*)&Ps[w][lane & 15][(lane >> 4) * 8];
#pragma unroll
      for (int df = 0; df < 8; ++df) {
        bf16x8 vb = *(const bf16x8*)&Vts[df * 16 + (lane & 15)][(lane >> 4) * 8];
        of[df] = __builtin_amdgcn_mfma_f32_16x16x32_bf16(pa, vb, of[df], 0, 0, 0);
      }
    }
  }

  // epilogue: D[q][d]: q=(lane>>4)*4+reg, d=(lane&15)+16*df
#pragma unroll
  for (int reg = 0; reg < 4; ++reg) {
    int gq = qbase + (lane >> 4) * 4 + reg;
    if (gq < S_TOT) {
      float inv = 1.0f / l_r[reg];
      ushort* orow =
          &attb[(long)(b * S_TOT + gq) * 512 + h * 128 + (lane & 15)];
#pragma unroll
      for (int df = 0; df < 8; ++df) orow[df * 16] = f2b(of[df][reg] * inv);
    }
  }
}

// ---------------------------------------------------------------- layernorm
__global__ __launch_bounds__(256) void ln_kernel(
    float* __restrict__ x, const float* __restrict__ add,
    const float* __restrict__ g, const float* __restrict__ bta,
    ushort* __restrict__ xb) {
  int row = blockIdx.x;
  int tid = threadIdx.x;
  long base = (long)row * 512;
  float v0 = x[base + tid] + add[base + tid];
  float v1 = x[base + 256 + tid] + add[base + 256 + tid];
  float s = v0 + v1;
  float s2 = v0 * v0 + v1 * v1;
  __shared__ float red[8];
#pragma unroll
  for (int o = 32; o > 0; o >>= 1) {
    s += __shfl_down(s, o);
    s2 += __shfl_down(s2, o);
  }
  int wid = tid >> 6;
  if ((tid & 63) == 0) { red[wid] = s; red[4 + wid] = s2; }
  __syncthreads();
  float ts = red[0] + red[1] + red[2] + red[3];
  float ts2 = red[4] + red[5] + red[6] + red[7];
  float mean = ts * (1.f / 512.f);
  float var = ts2 * (1.f / 512.f) - mean * mean;
  float inv = 1.0f / sqrtf(var + LN_EPS);
  float o0 = (v0 - mean) * inv * g[tid] + bta[tid];
  float o1 = (v1 - mean) * inv * g[256 + tid] + bta[256 + tid];
  x[base + tid] = o0;
  x[base + 256 + tid] = o1;
  xb[base + tid] = f2b(o0);
  xb[base + 256 + tid] = f2b(o1);
}

// ---------------------------------------------------------------- heads
__global__ __launch_bounds__(256) void head_cat_kernel(
    const float* __restrict__ x, const float* __restrict__ w_cat,
    float* __restrict__ out0) {
  __shared__ alignas(16) float Pc[16][260];
  __shared__ alignas(16) float Ws[16][260];
  int tid = threadIdx.x;
#pragma unroll
  for (int r = 0; r < 4; ++r) {
    int e = tid + r * 256;
    int rr = e >> 6, d4 = e & 63;
    int b = rr >> 1, p = rr & 1;
    *(float4*)&Pc[rr][d4 * 4] =
        *(const float4*)&x[((long)(b * S_TOT + SCTX + p)) * 512 + d4 * 4];
  }
  int n0 = blockIdx.x * 256;
  for (int nc = 0; nc < 256; nc += 16) {
    __syncthreads();
#pragma unroll
    for (int r = 0; r < 4; ++r) {
      int e = tid + r * 256;
      int rr = e >> 6, d4 = e & 63;
      int n = n0 + nc + rr;
      float4 w = make_float4(0.f, 0.f, 0.f, 0.f);
      if (n < 50000) w = *(const float4*)&w_cat[(long)n * 256 + d4 * 4];
      *(float4*)&Ws[rr][d4 * 4] = w;
    }
    __syncthreads();
    int rr = tid >> 4, nn = tid & 15;
    float sum = 0.f;
#pragma unroll 8
    for (int d4 = 0; d4 < 64; ++d4) {
      float4 a = *(const float4*)&Pc[rr][d4 * 4];
      float4 w = *(const float4*)&Ws[nn][d4 * 4];
      sum += a.x * w.x + a.y * w.y + a.z * w.z + a.w * w.w;
    }
    int n = n0 + nc + nn;
    int b = rr >> 1, p = rr & 1;
    if (n < 50000) out0[((long)(b * 2 + p)) * 50000 + n] = sum;
  }
}

__global__ __launch_bounds__(256) void head_cont_kernel(
    const float* __restrict__ x, float* __restrict__ out1,
    float* __restrict__ out2) {
  __shared__ alignas(16) float Pt[16][132];
  __shared__ alignas(16) float Pf[16][132];
  __shared__ alignas(16) float Ws[16][132];
  int tid = threadIdx.x;
#pragma unroll
  for (int r = 0; r < 2; ++r) {
    int e = tid + r * 256;
    int rr = e >> 5, d4 = e & 31;
    int b = rr >> 1, p = rr & 1;
    long base = ((long)(b * S_TOT + SCTX + p)) * 512;
    *(float4*)&Pt[rr][d4 * 4] = *(const float4*)&x[base + 256 + d4 * 4];
    *(float4*)&Pf[rr][d4 * 4] = *(const float4*)&x[base + 384 + d4 * 4];
  }
  int n0 = blockIdx.x * 256;
  for (int nc = 0; nc < 256; nc += 16) {
    __syncthreads();
#pragma unroll
    for (int r = 0; r < 8; ++r) {
      int e = tid + r * 256;
      int rr = e >> 7, i = e & 127;
      int n = n0 + nc + rr;
      float freq = expf(-(float)i * (6.907755278982137f / 128.f));  // 1000^(-i/128)
      float ang = (float)n * freq;
      Ws[rr][i] = (i & 1) ? cosf(ang) : sinf(ang);
    }
    __syncthreads();
    int rr = tid >> 4, nn = tid & 15;
    float s1 = 0.f, s2 = 0.f;
#pragma unroll 8
    for (int d4 = 0; d4 < 32; ++d4) {
      float4 w = *(const float4*)&Ws[nn][d4 * 4];
      float4 a = *(const float4*)&Pt[rr][d4 * 4];
      float4 c = *(const float4*)&Pf[rr][d4 * 4];
      s1 += a.x * w.x + a.y * w.y + a.z * w.z + a.w * w.w;
      s2 += c.x * w.x + c.y * w.y + c.z * w.z + c.w * w.w;
    }
    int n = n0 + nc + nn;
    int b = rr >> 1, p = rr & 1;
    out1[((long)(b * 2 + p)) * 4096 + n] = s1;
    out2[((long)(b * 2 + p)) * 4096 + n] = s2;
  }
}

// ---------------------------------------------------------------- launch
extern "C" void kernel_launch(void* const* d_in, const int* in_sizes, int n_in,
                              void* d_out, int out_size, void* d_ws,
                              size_t ws_size, hipStream_t stream) {
  const int* cat = (const int*)d_in[0];
  const int* timev = (const int*)d_in[1];
  const int* f0 = (const int*)d_in[2];
  const float* w_cat = (const float*)d_in[3];
  const float* pad_emb = (const float*)d_in[4];
  const float* attn_in_w = (const float*)d_in[5];
  const float* attn_in_b = (const float*)d_in[6];
  const float* attn_out_w = (const float*)d_in[7];
  const float* attn_out_b = (const float*)d_in[8];
  const float* ff1_w = (const float*)d_in[9];
  const float* ff1_b = (const float*)d_in[10];
  const float* ff2_w = (const float*)d_in[11];
  const float* ff2_b = (const float*)d_in[12];
  const float* ln1_g = (const float*)d_in[13];
  const float* ln1_b = (const float*)d_in[14];
  const float* ln2_g = (const float*)d_in[15];
  const float* ln2_b = (const float*)d_in[16];

  // -------- workspace layout: 180.5 MB total (unchanged from round 4) ----
  const size_t REQUIRED = 180518912ull;
  if (ws_size < REQUIRED) return;

  float* X = (float*)d_ws;                           // 16400*512 f32
  float* TMP = X + (long)M_ROWS * 512;               // 16400*512 f32 (also Vt home)
  ushort* Xb = (ushort*)(TMP + (long)M_ROWS * 512);  // 16400*512 bf16
  ushort* ATTb = Xb + (long)M_ROWS * 512;            // 16400*512 bf16
  ushort* U = ATTb + (long)M_ROWS * 512;  // union: QKV(16400*1536) / HMID(16400*2048)
  ushort* Wb_ain = U + (long)M_ROWS * 2048;   // 2*1536*512
  ushort* Wb_aout = Wb_ain + 2 * 1536 * 512;  // 2*512*512
  ushort* Wb_ff1 = Wb_aout + 2 * 512 * 512;   // 2*2048*512
  ushort* Wb_ff2 = Wb_ff1 + 2 * 2048 * 512;   // 2*512*2048
  // Vt (16.78 MB bf16) shares TMP (33.6 MB f32): disjoint live ranges
  ushort* Vtb = (ushort*)TMP;

  float* out0 = (float*)d_out;  // 8*2*50000
  float* out1 = out0 + 800000;  // 8*2*4096
  float* out2 = out1 + 65536;   // 8*2*4096

  cast_f32_bf16<<<1536, 256, 0, stream>>>(attn_in_w, Wb_ain, 2 * 1536 * 512 / 4);
  cast_f32_bf16<<<512, 256, 0, stream>>>(attn_out_w, Wb_aout, 2 * 512 * 512 / 4);
  cast_f32_bf16<<<2048, 256, 0, stream>>>(ff1_w, Wb_ff1, 2 * 2048 * 512 / 4);
  cast_f32_bf16<<<2048, 256, 0, stream>>>(ff2_w, Wb_ff2, 2 * 512 * 2048 / 4);

  embed_kernel<<<(M_ROWS * 512) / 256, 256, 0, stream>>>(cat, timev, f0, w_cat,
                                                         pad_emb, X, Xb);
  int mtiles = (M_ROWS + 127) / 128;  // 129
  for (int l = 0; l < NLAYER; ++l) {
    gemm_bf16<<<dim3(12, mtiles), 256, 0, stream>>>(
        Xb, Wb_ain + (long)l * 1536 * 512, attn_in_b + l * 1536, U, M_ROWS,
        1536, 512, 1, 0);  // QKV -> bf16 in U
    vt_kernel<<<4096, 256, 0, stream>>>(U, Vtb);
    attn_mfma<<<dim3(33, NHEAD, BATCH), 256, 0, stream>>>(U, Vtb, ATTb);
    gemm_bf16<<<dim3(4, mtiles), 256, 0, stream>>>(
        ATTb, Wb_aout + (long)l * 512 * 512, attn_out_b + l * 512, TMP, M_ROWS,
        512, 512, 0, 0);
    ln_kernel<<<M_ROWS, 256, 0, stream>>>(X, TMP, ln1_g + l * 512,
                                          ln1_b + l * 512, Xb);
    gemm_bf16<<<dim3(16, mtiles), 256, 0, stream>>>(
        Xb, Wb_ff1 + (long)l * 2048 * 512, ff1_b + l * 2048, U, M_ROWS, 2048,
        512, 1, 1);  // HMID -> bf16 relu in U
    gemm_bf16<<<dim3(4, mtiles), 256, 0, stream>>>(
        U, Wb_ff2 + (long)l * 512 * 2048, ff2_b + l * 512, TMP, M_ROWS, 512,
        2048, 0, 0);
    ln_kernel<<<M_ROWS, 256, 0, stream>>>(X, TMP, ln2_g + l * 512,
                                          ln2_b + l * 512, Xb);
  }
  head_cat_kernel<<<196, 256, 0, stream>>>(X, w_cat, out0);
  head_cont_kernel<<<16, 256, 0, stream>>>(X, out1, out2);
}

// Round 9
// 1200.894 us; speedup vs baseline: 3.7243x; 1.1670x over previous
//
#include <hip/hip_runtime.h>
#include <hip/hip_bf16.h>
#include <math.h>

#define D_MODEL 512
#define NHEAD 4
#define DHEAD 128
#define DFF 2048
#define NLAYER 2
#define SCTX 2048
#define PREDN 2
#define BATCH 8
#define S_TOT 2050              // SCTX + PREDN
#define M_ROWS (BATCH * S_TOT)  // 16400
#define LN_EPS 1e-5f
#define SCALE 0.08838834764831845f

typedef __attribute__((ext_vector_type(8))) short bf16x8;
typedef __attribute__((ext_vector_type(4))) float f32x4;

__device__ inline ushort f2b(float f) {
  union { __hip_bfloat16 b; ushort u; } cv;
  cv.b = __float2bfloat16(f);
  return cv.u;
}
__device__ inline float b2f(ushort u) {
  union { float f; unsigned int i; } cv;
  cv.i = ((unsigned int)u) << 16;
  return cv.f;
}

// async global->LDS, 16B per lane; LDS dest = wave-uniform base + lane*16
typedef const __attribute__((address_space(1))) void* gas_ptr;
typedef __attribute__((address_space(3))) void* las_ptr;
__device__ __forceinline__ void gload16(const void* g, void* l) {
  __builtin_amdgcn_global_load_lds((gas_ptr)g, (las_ptr)l, 16, 0, 0);
}

// ---------------------------------------------------------------- cast
__global__ __launch_bounds__(256) void cast_f32_bf16(
    const float* __restrict__ in, ushort* __restrict__ out, int n4) {
  int i = blockIdx.x * 256 + threadIdx.x;
  if (i >= n4) return;
  float4 v = *(const float4*)&in[(long)i * 4];
  ushort4 o;
  o.x = f2b(v.x); o.y = f2b(v.y); o.z = f2b(v.z); o.w = f2b(v.w);
  *(ushort4*)&out[(long)i * 4] = o;
}

// ---------------------------------------------------------------- embedding
__global__ __launch_bounds__(256) void embed_kernel(
    const int* __restrict__ cat, const int* __restrict__ timev,
    const int* __restrict__ f0, const float* __restrict__ w_cat,
    const float* __restrict__ pad_emb, float* __restrict__ x,
    ushort* __restrict__ xb) {
  int idx = blockIdx.x * 256 + threadIdx.x;  // over M_ROWS * 512
  if (idx >= M_ROWS * D_MODEL) return;
  int d = idx & (D_MODEL - 1);
  int row = idx >> 9;
  int b = row / S_TOT;
  int s = row - b * S_TOT;
  float val;
  if (s >= SCTX) {
    val = pad_emb[d];
  } else if (d < 256) {
    int c = cat[b * SCTX + s];
    val = w_cat[(long)c * 256 + d];
  } else {
    int i = (d < 384) ? (d - 256) : (d - 384);
    int v = (d < 384) ? timev[b * SCTX + s] : f0[b * SCTX + s];
    float freq = expf(-(float)i * (9.210340371976184f / 128.0f));  // 10000^(-i/128)
    float ang = (float)v * freq;
    val = (i & 1) ? cosf(ang) : sinf(ang);
  }
  x[idx] = val;
  xb[idx] = f2b(val);
}

// ---------------------------------------------------------------- MFMA GEMM
// C[M,N] = A[M,K] @ W[N,K]^T + bias[N]. m97 structure: global_load_lds(16B)
// into linear LDS, 128x128 tile, BK=32, 4 waves x 64x64 sub-tile.
__global__ __launch_bounds__(256) void gemm_bf16(
    const ushort* __restrict__ A, const ushort* __restrict__ W,
    const float* __restrict__ bias, void* __restrict__ Cout,
    int M, int N, int K, int out_bf16, int relu) {
  __shared__ alignas(16) ushort As[128][32];
  __shared__ alignas(16) ushort Bs[128][32];
  int tid = threadIdx.x;
  int lane = tid & 63;
  int wv = tid >> 6;
  int wr = wv >> 1, wc = wv & 1;
  int m0 = blockIdx.y * 128, n0 = blockIdx.x * 128;
  f32x4 acc[4][4];
#pragma unroll
  for (int m = 0; m < 4; ++m)
#pragma unroll
    for (int n = 0; n < 4; ++n) acc[m][n] = (f32x4){0.f, 0.f, 0.f, 0.f};

  int r_ld = lane & 15;
  int g_ld = lane >> 4;

  for (int k0 = 0; k0 < K; k0 += 32) {
    // stage: each wave-call covers 16 rows x 32 cols (1024 B), linear LDS
#pragma unroll
    for (int c = 0; c < 2; ++c) {
      int row = c * 64 + wv * 16 + (lane >> 2);
      int col = k0 + (lane & 3) * 8;
      int ga = m0 + row; if (ga > M - 1) ga = M - 1;  // clamp (no OOB)
      gload16(&A[(long)ga * K + col], &As[c * 64 + wv * 16][0]);
      int gb = n0 + row; if (gb > N - 1) gb = N - 1;
      gload16(&W[(long)gb * K + col], &Bs[c * 64 + wv * 16][0]);
    }
    __syncthreads();
    bf16x8 af[4], bfr[4];
#pragma unroll
    for (int m = 0; m < 4; ++m)
      af[m] = *(const bf16x8*)&As[wr * 64 + m * 16 + r_ld][g_ld * 8];
#pragma unroll
    for (int n = 0; n < 4; ++n)
      bfr[n] = *(const bf16x8*)&Bs[wc * 64 + n * 16 + r_ld][g_ld * 8];
#pragma unroll
    for (int m = 0; m < 4; ++m)
#pragma unroll
      for (int n = 0; n < 4; ++n)
        acc[m][n] = __builtin_amdgcn_mfma_f32_16x16x32_bf16(af[m], bfr[n],
                                                            acc[m][n], 0, 0, 0);
    __syncthreads();
  }
  // epilogue: C/D layout col=lane&15, row=(lane>>4)*4+reg  [m89/m91]
  int r4 = lane >> 4, cc = lane & 15;
#pragma unroll
  for (int m = 0; m < 4; ++m) {
#pragma unroll
    for (int n = 0; n < 4; ++n) {
      int gn = n0 + wc * 64 + n * 16 + cc;
      float bv = bias[gn];
#pragma unroll
      for (int reg = 0; reg < 4; ++reg) {
        int gm = m0 + wr * 64 + m * 16 + r4 * 4 + reg;
        if (gm >= M) continue;
        float v = acc[m][n][reg] + bv;
        if (relu) v = fmaxf(v, 0.f);
        if (out_bf16)
          ((ushort*)Cout)[(long)gm * N + gn] = f2b(v);
        else
          ((float*)Cout)[(long)gm * N + gn] = v;
      }
    }
  }
}

// ---------------------------------------------------------------- V transpose
// Vt[(b*4+h)*128 + d][s] = V[b, s, h, d], s in [0,2048). Coalesced via LDS.
__global__ __launch_bounds__(256) void vt_kernel(
    const ushort* __restrict__ qkv, ushort* __restrict__ vt) {
  int st = blockIdx.x;  // 32 s-tiles of 64
  int h = blockIdx.y, b = blockIdx.z;
  int s0 = st * 64;
  __shared__ alignas(16) ushort T[64][136];  // pad 8: row stride 272 B
  int tid = threadIdx.x;
#pragma unroll
  for (int it = 0; it < 4; ++it) {
    int e = tid + it * 256;  // int4 slots over 64 rows x 16
    int row = e >> 4, c8 = e & 15;
    long g = (long)(b * S_TOT + s0 + row) * 1536 + 1024 + h * 128 + c8 * 8;
    *(int4*)&T[row][c8 * 8] = *(const int4*)&qkv[g];
  }
  __syncthreads();
  int d = tid >> 1, sh = (tid & 1) * 32;
  ushort tmp[32];
#pragma unroll
  for (int j = 0; j < 32; ++j) tmp[j] = T[sh + j][d];
  ushort* dst = &vt[((long)((b * NHEAD + h) * 128 + d)) * 2048 + s0 + sh];
#pragma unroll
  for (int j4 = 0; j4 < 8; ++j4) {
    ushort4 o; o.x = tmp[j4 * 4]; o.y = tmp[j4 * 4 + 1];
    o.z = tmp[j4 * 4 + 2]; o.w = tmp[j4 * 4 + 3];
    *(ushort4*)&dst[j4 * 4] = o;
  }
}

// ---------------------------------------------------------------- attention
// MFMA flash attn. Block = 64 q rows (4 waves x 16), KV tiles of 32.
// Double-buffered K/V via global_load_lds (1 barrier/tile); XOR-swizzled LDS
// (linear dest + pre-swizzled global source + swizzled read  [ERRATA 21]).
__global__ __launch_bounds__(256) void attn_mfma(
    const ushort* __restrict__ qkv, const ushort* __restrict__ vt,
    ushort* __restrict__ attb) {
  int qt = blockIdx.x, h = blockIdx.y, b = blockIdx.z;
  int q0 = qt * 64;
  int tid = threadIdx.x;
  int lane = tid & 63;
  int w = tid >> 6;
  int qbase = q0 + w * 16;
  int l15 = lane & 15, hi = lane >> 4;

  __shared__ alignas(16) ushort Ks[2][32][128];   // 16 KB
  __shared__ alignas(16) ushort Vts[2][128][32];  // 16 KB
  __shared__ alignas(16) ushort Ps[4][16][40];    // 5 KB (wave-local)

  // Q fragments: A[row=q=l15][k=d=hi*8 + ks*32]
  bf16x8 qf[4];
  {
    int gq = qbase + l15;
    if (gq > S_TOT - 1) gq = S_TOT - 1;
    const ushort* qrow = &qkv[(long)(b * S_TOT + gq) * 1536 + h * 128 + hi * 8];
#pragma unroll
    for (int ks = 0; ks < 4; ++ks) qf[ks] = *(const bf16x8*)&qrow[ks * 32];
  }

  f32x4 of[8];
#pragma unroll
  for (int df = 0; df < 8; ++df) of[df] = (f32x4){0.f, 0.f, 0.f, 0.f};
  float m_r[4] = {-3e38f, -3e38f, -3e38f, -3e38f};
  float l_r[4] = {0.f, 0.f, 0.f, 0.f};

  int kmax_blk = min(q0 + 63, SCTX - 1);
  int ktn = (kmax_blk >> 5) + 1;
  int wave_qmax = qbase + 15;

  // stage tile kt_ into buffer bb_: K rows 256B (16 chunks), Vt rows 64B (4)
#define STAGE(kt_, bb_)                                                        \
  {                                                                            \
    int k0s = (kt_) * 32;                                                      \
    _Pragma("unroll") for (int c = 0; c < 2; ++c) {                            \
      int rk = c * 16 + w * 4 + hi;                                            \
      int ck = l15 ^ (rk & 7);                                                 \
      gload16(&qkv[(long)(b * S_TOT + k0s + rk) * 1536 + 512 + h * 128 +       \
                   ck * 8],                                                    \
              &Ks[bb_][c * 16 + w * 4][0]);                                    \
      int rv = c * 64 + w * 16 + (lane >> 2);                                  \
      int cv = (lane & 3) ^ ((rv >> 1) & 3);                                   \
      gload16(&vt[((long)((b * NHEAD + h) * 128 + rv)) * 2048 + k0s + cv * 8], \
              &Vts[bb_][c * 64 + w * 16][0]);                                  \
    }                                                                          \
  }

  STAGE(0, 0);
  __syncthreads();
  int cur = 0;
  for (int kt = 0; kt < ktn; ++kt) {
    int k0 = kt * 32;
    if (kt + 1 < ktn) STAGE(kt + 1, cur ^ 1);  // prefetch hides under compute
    bool active = (k0 <= wave_qmax);
    if (active) {
      // QK^T: D[q][key], q=hi*4+reg (A-side), key=l15 (+16)
      f32x4 sf0 = (f32x4){0.f, 0.f, 0.f, 0.f};
      f32x4 sf1 = (f32x4){0.f, 0.f, 0.f, 0.f};
#pragma unroll
      for (int ks = 0; ks < 4; ++ks) {
        int ch = ((hi + ks * 4) ^ (l15 & 7)) * 8;  // swizzled chunk
        bf16x8 kf0 = *(const bf16x8*)&Ks[cur][l15][ch];
        bf16x8 kf1 = *(const bf16x8*)&Ks[cur][16 + l15][ch];
        sf0 = __builtin_amdgcn_mfma_f32_16x16x32_bf16(qf[ks], kf0, sf0, 0, 0, 0);
        sf1 = __builtin_amdgcn_mfma_f32_16x16x32_bf16(qf[ks], kf1, sf1, 0, 0, 0);
      }
      int kbase = k0 + l15;
#pragma unroll
      for (int reg = 0; reg < 4; ++reg) {
        int ql = hi * 4 + reg;
        int gq = qbase + ql;
        bool v0 = (kbase <= gq) && (kbase <= SCTX - 1);
        bool v1 = (kbase + 16 <= gq) && (kbase + 16 <= SCTX - 1);
        float s0 = sf0[reg] * SCALE;
        float s1 = sf1[reg] * SCALE;
        float mx = fmaxf(v0 ? s0 : -3e38f, v1 ? s1 : -3e38f);
#pragma unroll
        for (int off = 1; off < 16; off <<= 1)
          mx = fmaxf(mx, __shfl_xor(mx, off));
        float mo = m_r[reg];
        float mn = fmaxf(mo, mx);
        float cf = __expf(mo - mn);
        float p0 = v0 ? __expf(s0 - mn) : 0.f;
        float p1 = v1 ? __expf(s1 - mn) : 0.f;
        float rs = p0 + p1;
#pragma unroll
        for (int off = 1; off < 16; off <<= 1) rs += __shfl_xor(rs, off);
        l_r[reg] = l_r[reg] * cf + rs;
        m_r[reg] = mn;
#pragma unroll
        for (int df = 0; df < 8; ++df) of[df][reg] *= cf;
        Ps[w][ql][l15] = f2b(p0);
        Ps[w][ql][16 + l15] = f2b(p1);
      }
      // PV: A=P[q=l15][key=hi*8+j], B=Vt[d][key] -> D[q][d]  (wave-local P)
      bf16x8 pa = *(const bf16x8*)&Ps[w][l15][hi * 8];
#pragma unroll
      for (int df = 0; df < 8; ++df) {
        int d = df * 16 + l15;
        bf16x8 vb = *(const bf16x8*)&Vts[cur][d][(hi ^ ((d >> 1) & 3)) * 8];
        of[df] = __builtin_amdgcn_mfma_f32_16x16x32_bf16(pa, vb, of[df], 0, 0, 0);
      }
    }
    __syncthreads();  // staged tile landed + all waves done with cur
    cur ^= 1;
  }
#undef STAGE

  // epilogue: D[q][d]: q=hi*4+reg, d=l15+16*df
#pragma unroll
  for (int reg = 0; reg < 4; ++reg) {
    int gq = qbase + hi * 4 + reg;
    if (gq < S_TOT) {
      float inv = 1.0f / l_r[reg];
      ushort* orow = &attb[(long)(b * S_TOT + gq) * 512 + h * 128 + l15];
#pragma unroll
      for (int df = 0; df < 8; ++df) orow[df * 16] = f2b(of[df][reg] * inv);
    }
  }
}

// ---------------------------------------------------------------- layernorm
__global__ __launch_bounds__(256) void ln_kernel(
    float* __restrict__ x, const float* __restrict__ add,
    const float* __restrict__ g, const float* __restrict__ bta,
    ushort* __restrict__ xb) {
  int row = blockIdx.x;
  int tid = threadIdx.x;
  long base = (long)row * 512;
  float v0 = x[base + tid] + add[base + tid];
  float v1 = x[base + 256 + tid] + add[base + 256 + tid];
  float s = v0 + v1;
  float s2 = v0 * v0 + v1 * v1;
  __shared__ float red[8];
#pragma unroll
  for (int o = 32; o > 0; o >>= 1) {
    s += __shfl_down(s, o);
    s2 += __shfl_down(s2, o);
  }
  int wid = tid >> 6;
  if ((tid & 63) == 0) { red[wid] = s; red[4 + wid] = s2; }
  __syncthreads();
  float ts = red[0] + red[1] + red[2] + red[3];
  float ts2 = red[4] + red[5] + red[6] + red[7];
  float mean = ts * (1.f / 512.f);
  float var = ts2 * (1.f / 512.f) - mean * mean;
  float inv = 1.0f / sqrtf(var + LN_EPS);
  float o0 = (v0 - mean) * inv * g[tid] + bta[tid];
  float o1 = (v1 - mean) * inv * g[256 + tid] + bta[256 + tid];
  x[base + tid] = o0;
  x[base + 256 + tid] = o1;
  xb[base + tid] = f2b(o0);
  xb[base + 256 + tid] = f2b(o1);
}

// ---------------------------------------------------------------- heads
__global__ __launch_bounds__(256) void head_cat_kernel(
    const float* __restrict__ x, const float* __restrict__ w_cat,
    float* __restrict__ out0) {
  __shared__ alignas(16) float Pc[16][260];
  __shared__ alignas(16) float Ws[16][260];
  int tid = threadIdx.x;
#pragma unroll
  for (int r = 0; r < 4; ++r) {
    int e = tid + r * 256;
    int rr = e >> 6, d4 = e & 63;
    int b = rr >> 1, p = rr & 1;
    *(float4*)&Pc[rr][d4 * 4] =
        *(const float4*)&x[((long)(b * S_TOT + SCTX + p)) * 512 + d4 * 4];
  }
  int n0 = blockIdx.x * 256;
  for (int nc = 0; nc < 256; nc += 16) {
    __syncthreads();
#pragma unroll
    for (int r = 0; r < 4; ++r) {
      int e = tid + r * 256;
      int rr = e >> 6, d4 = e & 63;
      int n = n0 + nc + rr;
      float4 w = make_float4(0.f, 0.f, 0.f, 0.f);
      if (n < 50000) w = *(const float4*)&w_cat[(long)n * 256 + d4 * 4];
      *(float4*)&Ws[rr][d4 * 4] = w;
    }
    __syncthreads();
    int rr = tid >> 4, nn = tid & 15;
    float sum = 0.f;
#pragma unroll 8
    for (int d4 = 0; d4 < 64; ++d4) {
      float4 a = *(const float4*)&Pc[rr][d4 * 4];
      float4 w = *(const float4*)&Ws[nn][d4 * 4];
      sum += a.x * w.x + a.y * w.y + a.z * w.z + a.w * w.w;
    }
    int n = n0 + nc + nn;
    int b = rr >> 1, p = rr & 1;
    if (n < 50000) out0[((long)(b * 2 + p)) * 50000 + n] = sum;
  }
}

__global__ __launch_bounds__(256) void head_cont_kernel(
    const float* __restrict__ x, float* __restrict__ out1,
    float* __restrict__ out2) {
  __shared__ alignas(16) float Pt[16][132];
  __shared__ alignas(16) float Pf[16][132];
  __shared__ alignas(16) float Ws[16][132];
  int tid = threadIdx.x;
#pragma unroll
  for (int r = 0; r < 2; ++r) {
    int e = tid + r * 256;
    int rr = e >> 5, d4 = e & 31;
    int b = rr >> 1, p = rr & 1;
    long base = ((long)(b * S_TOT + SCTX + p)) * 512;
    *(float4*)&Pt[rr][d4 * 4] = *(const float4*)&x[base + 256 + d4 * 4];
    *(float4*)&Pf[rr][d4 * 4] = *(const float4*)&x[base + 384 + d4 * 4];
  }
  int n0 = blockIdx.x * 256;
  for (int nc = 0; nc < 256; nc += 16) {
    __syncthreads();
#pragma unroll
    for (int r = 0; r < 8; ++r) {
      int e = tid + r * 256;
      int rr = e >> 7, i = e & 127;
      int n = n0 + nc + rr;
      float freq = expf(-(float)i * (6.907755278982137f / 128.f));  // 1000^(-i/128)
      float ang = (float)n * freq;
      Ws[rr][i] = (i & 1) ? cosf(ang) : sinf(ang);
    }
    __syncthreads();
    int rr = tid >> 4, nn = tid & 15;
    float s1 = 0.f, s2 = 0.f;
#pragma unroll 8
    for (int d4 = 0; d4 < 32; ++d4) {
      float4 w = *(const float4*)&Ws[nn][d4 * 4];
      float4 a = *(const float4*)&Pt[rr][d4 * 4];
      float4 c = *(const float4*)&Pf[rr][d4 * 4];
      s1 += a.x * w.x + a.y * w.y + a.z * w.z + a.w * w.w;
      s2 += c.x * w.x + c.y * w.y + c.z * w.z + c.w * w.w;
    }
    int n = n0 + nc + nn;
    int b = rr >> 1, p = rr & 1;
    out1[((long)(b * 2 + p)) * 4096 + n] = s1;
    out2[((long)(b * 2 + p)) * 4096 + n] = s2;
  }
}

// ---------------------------------------------------------------- launch
extern "C" void kernel_launch(void* const* d_in, const int* in_sizes, int n_in,
                              void* d_out, int out_size, void* d_ws,
                              size_t ws_size, hipStream_t stream) {
  const int* cat = (const int*)d_in[0];
  const int* timev = (const int*)d_in[1];
  const int* f0 = (const int*)d_in[2];
  const float* w_cat = (const float*)d_in[3];
  const float* pad_emb = (const float*)d_in[4];
  const float* attn_in_w = (const float*)d_in[5];
  const float* attn_in_b = (const float*)d_in[6];
  const float* attn_out_w = (const float*)d_in[7];
  const float* attn_out_b = (const float*)d_in[8];
  const float* ff1_w = (const float*)d_in[9];
  const float* ff1_b = (const float*)d_in[10];
  const float* ff2_w = (const float*)d_in[11];
  const float* ff2_b = (const float*)d_in[12];
  const float* ln1_g = (const float*)d_in[13];
  const float* ln1_b = (const float*)d_in[14];
  const float* ln2_g = (const float*)d_in[15];
  const float* ln2_b = (const float*)d_in[16];

  // -------- workspace layout: 180.5 MB total (unchanged) --------
  const size_t REQUIRED = 180518912ull;
  if (ws_size < REQUIRED) return;

  float* X = (float*)d_ws;                           // 16400*512 f32
  float* TMP = X + (long)M_ROWS * 512;               // 16400*512 f32 (also Vt home)
  ushort* Xb = (ushort*)(TMP + (long)M_ROWS * 512);  // 16400*512 bf16
  ushort* ATTb = Xb + (long)M_ROWS * 512;            // 16400*512 bf16
  ushort* U = ATTb + (long)M_ROWS * 512;  // union: QKV(16400*1536) / HMID(16400*2048)
  ushort* Wb_ain = U + (long)M_ROWS * 2048;   // 2*1536*512
  ushort* Wb_aout = Wb_ain + 2 * 1536 * 512;  // 2*512*512
  ushort* Wb_ff1 = Wb_aout + 2 * 512 * 512;   // 2*2048*512
  ushort* Wb_ff2 = Wb_ff1 + 2 * 2048 * 512;   // 2*512*2048
  ushort* Vtb = (ushort*)TMP;  // Vt (16.78 MB) shares TMP: disjoint live ranges

  float* out0 = (float*)d_out;  // 8*2*50000
  float* out1 = out0 + 800000;  // 8*2*4096
  float* out2 = out1 + 65536;   // 8*2*4096

  cast_f32_bf16<<<1536, 256, 0, stream>>>(attn_in_w, Wb_ain, 2 * 1536 * 512 / 4);
  cast_f32_bf16<<<512, 256, 0, stream>>>(attn_out_w, Wb_aout, 2 * 512 * 512 / 4);
  cast_f32_bf16<<<2048, 256, 0, stream>>>(ff1_w, Wb_ff1, 2 * 2048 * 512 / 4);
  cast_f32_bf16<<<2048, 256, 0, stream>>>(ff2_w, Wb_ff2, 2 * 512 * 2048 / 4);

  embed_kernel<<<(M_ROWS * 512) / 256, 256, 0, stream>>>(cat, timev, f0, w_cat,
                                                         pad_emb, X, Xb);
  int mtiles = (M_ROWS + 127) / 128;  // 129
  for (int l = 0; l < NLAYER; ++l) {
    gemm_bf16<<<dim3(12, mtiles), 256, 0, stream>>>(
        Xb, Wb_ain + (long)l * 1536 * 512, attn_in_b + l * 1536, U, M_ROWS,
        1536, 512, 1, 0);  // QKV -> bf16 in U
    vt_kernel<<<dim3(32, NHEAD, BATCH), 256, 0, stream>>>(U, Vtb);
    attn_mfma<<<dim3(33, NHEAD, BATCH), 256, 0, stream>>>(U, Vtb, ATTb);
    gemm_bf16<<<dim3(4, mtiles), 256, 0, stream>>>(
        ATTb, Wb_aout + (long)l * 512 * 512, attn_out_b + l * 512, TMP, M_ROWS,
        512, 512, 0, 0);
    ln_kernel<<<M_ROWS, 256, 0, stream>>>(X, TMP, ln1_g + l * 512,
                                          ln1_b + l * 512, Xb);
    gemm_bf16<<<dim3(16, mtiles), 256, 0, stream>>>(
        Xb, Wb_ff1 + (long)l * 2048 * 512, ff1_b + l * 2048, U, M_ROWS, 2048,
        512, 1, 1);  // HMID -> bf16 relu in U
    gemm_bf16<<<dim3(4, mtiles), 256, 0, stream>>>(
        U, Wb_ff2 + (long)l * 512 * 2048, ff2_b + l * 512, TMP, M_ROWS, 512,
        2048, 0, 0);
    ln_kernel<<<M_ROWS, 256, 0, stream>>>(X, TMP, ln2_g + l * 512,
                                          ln2_b + l * 512, Xb);
  }
  head_cat_kernel<<<196, 256, 0, stream>>>(X, w_cat, out0);
  head_cont_kernel<<<16, 256, 0, stream>>>(X, out1, out2);
}

// Round 14
// 1183.115 us; speedup vs baseline: 3.7803x; 1.0150x over previous
//
#include <hip/hip_runtime.h>
#include <hip/hip_bf16.h>
#include <math.h>

#define D_MODEL 512
#define NHEAD 4
#define DHEAD 128
#define DFF 2048
#define NLAYER 2
#define SCTX 2048
#define PREDN 2
#define BATCH 8
#define S_TOT 2050              // SCTX + PREDN
#define M_ROWS (BATCH * S_TOT)  // 16400
#define LN_EPS 1e-5f
#define SCALE 0.08838834764831845f

typedef __attribute__((ext_vector_type(8))) short bf16x8;
typedef __attribute__((ext_vector_type(4))) float f32x4;

__device__ inline ushort f2b(float f) {
  union { __hip_bfloat16 b; ushort u; } cv;
  cv.b = __float2bfloat16(f);
  return cv.u;
}
__device__ inline float b2f(ushort u) {
  union { float f; unsigned int i; } cv;
  cv.i = ((unsigned int)u) << 16;
  return cv.f;
}

// async global->LDS, 16B per lane; LDS dest = wave-uniform base + lane*16
typedef const __attribute__((address_space(1))) void* gas_ptr;
typedef __attribute__((address_space(3))) void* las_ptr;
__device__ __forceinline__ void gload16(const void* g, void* l) {
  __builtin_amdgcn_global_load_lds((gas_ptr)g, (las_ptr)l, 16, 0, 0);
}

// ---------------------------------------------------------------- cast
__global__ __launch_bounds__(256) void cast_f32_bf16(
    const float* __restrict__ in, ushort* __restrict__ out, int n4) {
  int i = blockIdx.x * 256 + threadIdx.x;
  if (i >= n4) return;
  float4 v = *(const float4*)&in[(long)i * 4];
  ushort4 o;
  o.x = f2b(v.x); o.y = f2b(v.y); o.z = f2b(v.z); o.w = f2b(v.w);
  *(ushort4*)&out[(long)i * 4] = o;
}

// ---------------------------------------------------------------- embedding
__global__ __launch_bounds__(256) void embed_kernel(
    const int* __restrict__ cat, const int* __restrict__ timev,
    const int* __restrict__ f0, const float* __restrict__ w_cat,
    const float* __restrict__ pad_emb, float* __restrict__ x,
    ushort* __restrict__ xb) {
  int idx = blockIdx.x * 256 + threadIdx.x;  // over M_ROWS * 512
  if (idx >= M_ROWS * D_MODEL) return;
  int d = idx & (D_MODEL - 1);
  int row = idx >> 9;
  int b = row / S_TOT;
  int s = row - b * S_TOT;
  float val;
  if (s >= SCTX) {
    val = pad_emb[d];
  } else if (d < 256) {
    int c = cat[b * SCTX + s];
    val = w_cat[(long)c * 256 + d];
  } else {
    int i = (d < 384) ? (d - 256) : (d - 384);
    int v = (d < 384) ? timev[b * SCTX + s] : f0[b * SCTX + s];
    float freq = expf(-(float)i * (9.210340371976184f / 128.0f));  // 10000^(-i/128)
    float ang = (float)v * freq;
    val = (i & 1) ? cosf(ang) : sinf(ang);
  }
  x[idx] = val;
  xb[idx] = f2b(val);
}

// ---------------------------------------------------------------- MFMA GEMM
// C[M,N] = A[M,K] @ W[N,K]^T + bias[N]. m97 structure: global_load_lds(16B)
// into linear LDS, 128x128 tile, BK=32, 4 waves x 64x64 sub-tile.
__global__ __launch_bounds__(256) void gemm_bf16(
    const ushort* __restrict__ A, const ushort* __restrict__ W,
    const float* __restrict__ bias, void* __restrict__ Cout,
    int M, int N, int K, int out_bf16, int relu) {
  __shared__ alignas(16) ushort As[128][32];
  __shared__ alignas(16) ushort Bs[128][32];
  int tid = threadIdx.x;
  int lane = tid & 63;
  int wv = tid >> 6;
  int wr = wv >> 1, wc = wv & 1;
  int m0 = blockIdx.y * 128, n0 = blockIdx.x * 128;
  f32x4 acc[4][4];
#pragma unroll
  for (int m = 0; m < 4; ++m)
#pragma unroll
    for (int n = 0; n < 4; ++n) acc[m][n] = (f32x4){0.f, 0.f, 0.f, 0.f};

  int r_ld = lane & 15;
  int g_ld = lane >> 4;

  for (int k0 = 0; k0 < K; k0 += 32) {
    // stage: each wave-call covers 16 rows x 32 cols (1024 B), linear LDS
#pragma unroll
    for (int c = 0; c < 2; ++c) {
      int row = c * 64 + wv * 16 + (lane >> 2);
      int col = k0 + (lane & 3) * 8;
      int ga = m0 + row; if (ga > M - 1) ga = M - 1;  // clamp (no OOB)
      gload16(&A[(long)ga * K + col], &As[c * 64 + wv * 16][0]);
      int gb = n0 + row; if (gb > N - 1) gb = N - 1;
      gload16(&W[(long)gb * K + col], &Bs[c * 64 + wv * 16][0]);
    }
    __syncthreads();
    bf16x8 af[4], bfr[4];
#pragma unroll
    for (int m = 0; m < 4; ++m)
      af[m] = *(const bf16x8*)&As[wr * 64 + m * 16 + r_ld][g_ld * 8];
#pragma unroll
    for (int n = 0; n < 4; ++n)
      bfr[n] = *(const bf16x8*)&Bs[wc * 64 + n * 16 + r_ld][g_ld * 8];
#pragma unroll
    for (int m = 0; m < 4; ++m)
#pragma unroll
      for (int n = 0; n < 4; ++n)
        acc[m][n] = __builtin_amdgcn_mfma_f32_16x16x32_bf16(af[m], bfr[n],
                                                            acc[m][n], 0, 0, 0);
    __syncthreads();
  }
  // epilogue: C/D layout col=lane&15, row=(lane>>4)*4+reg  [m89/m91]
  int r4 = lane >> 4, cc = lane & 15;
#pragma unroll
  for (int m = 0; m < 4; ++m) {
#pragma unroll
    for (int n = 0; n < 4; ++n) {
      int gn = n0 + wc * 64 + n * 16 + cc;
      float bv = bias[gn];
#pragma unroll
      for (int reg = 0; reg < 4; ++reg) {
        int gm = m0 + wr * 64 + m * 16 + r4 * 4 + reg;
        if (gm >= M) continue;
        float v = acc[m][n][reg] + bv;
        if (relu) v = fmaxf(v, 0.f);
        if (out_bf16)
          ((ushort*)Cout)[(long)gm * N + gn] = f2b(v);
        else
          ((float*)Cout)[(long)gm * N + gn] = v;
      }
    }
  }
}

// ---------------------------------------------------------------- V transpose
// Vt[(b*4+h)*128 + d][s] = V[b, s, h, d], s in [0,2048). Coalesced via LDS.
__global__ __launch_bounds__(256) void vt_kernel(
    const ushort* __restrict__ qkv, ushort* __restrict__ vt) {
  int st = blockIdx.x;  // 32 s-tiles of 64
  int h = blockIdx.y, b = blockIdx.z;
  int s0 = st * 64;
  __shared__ alignas(16) ushort T[64][136];  // pad 8: row stride 272 B
  int tid = threadIdx.x;
#pragma unroll
  for (int it = 0; it < 4; ++it) {
    int e = tid + it * 256;  // int4 slots over 64 rows x 16
    int row = e >> 4, c8 = e & 15;
    long g = (long)(b * S_TOT + s0 + row) * 1536 + 1024 + h * 128 + c8 * 8;
    *(int4*)&T[row][c8 * 8] = *(const int4*)&qkv[g];
  }
  __syncthreads();
  int d = tid >> 1, sh = (tid & 1) * 32;
  ushort tmp[32];
#pragma unroll
  for (int j = 0; j < 32; ++j) tmp[j] = T[sh + j][d];
  ushort* dst = &vt[((long)((b * NHEAD + h) * 128 + d)) * 2048 + s0 + sh];
#pragma unroll
  for (int j4 = 0; j4 < 8; ++j4) {
    ushort4 o; o.x = tmp[j4 * 4]; o.y = tmp[j4 * 4 + 1];
    o.z = tmp[j4 * 4 + 2]; o.w = tmp[j4 * 4 + 3];
    *(ushort4*)&dst[j4 * 4] = o;
  }
}

// ---------------------------------------------------------------- attention
// MFMA flash attn (round-9 proven-stable version). Block = 64 q rows
// (4 waves x 16), KV tiles of 32, double-buffered global_load_lds
// (1 barrier/tile), XOR-swizzled LDS (linear dest + pre-swizzled global
// source + swizzled read  [ERRATA 21]).
__global__ __launch_bounds__(256) void attn_mfma(
    const ushort* __restrict__ qkv, const ushort* __restrict__ vt,
    ushort* __restrict__ attb) {
  int qt = blockIdx.x, h = blockIdx.y, b = blockIdx.z;
  int q0 = qt * 64;
  int tid = threadIdx.x;
  int lane = tid & 63;
  int w = tid >> 6;
  int qbase = q0 + w * 16;
  int l15 = lane & 15, hi = lane >> 4;

  __shared__ alignas(16) ushort Ks[2][32][128];   // 16 KB
  __shared__ alignas(16) ushort Vts[2][128][32];  // 16 KB
  __shared__ alignas(16) ushort Ps[4][16][40];    // 5 KB (wave-local)

  // Q fragments: A[row=q=l15][k=d=hi*8 + ks*32]
  bf16x8 qf[4];
  {
    int gq = qbase + l15;
    if (gq > S_TOT - 1) gq = S_TOT - 1;
    const ushort* qrow = &qkv[(long)(b * S_TOT + gq) * 1536 + h * 128 + hi * 8];
#pragma unroll
    for (int ks = 0; ks < 4; ++ks) qf[ks] = *(const bf16x8*)&qrow[ks * 32];
  }

  f32x4 of[8];
#pragma unroll
  for (int df = 0; df < 8; ++df) of[df] = (f32x4){0.f, 0.f, 0.f, 0.f};
  float m_r[4] = {-3e38f, -3e38f, -3e38f, -3e38f};
  float l_r[4] = {0.f, 0.f, 0.f, 0.f};

  int kmax_blk = min(q0 + 63, SCTX - 1);
  int ktn = (kmax_blk >> 5) + 1;
  int wave_qmax = qbase + 15;

  // stage tile kt_ into buffer bb_: K rows 256B (16 chunks), Vt rows 64B (4)
#define STAGE(kt_, bb_)                                                        \
  {                                                                            \
    int k0s = (kt_) * 32;                                                      \
    _Pragma("unroll") for (int c = 0; c < 2; ++c) {                            \
      int rk = c * 16 + w * 4 + hi;                                            \
      int ck = l15 ^ (rk & 7);                                                 \
      gload16(&qkv[(long)(b * S_TOT + k0s + rk) * 1536 + 512 + h * 128 +       \
                   ck * 8],                                                    \
              &Ks[bb_][c * 16 + w * 4][0]);                                    \
      int rv = c * 64 + w * 16 + (lane >> 2);                                  \
      int cv = (lane & 3) ^ ((rv >> 1) & 3);                                   \
      gload16(&vt[((long)((b * NHEAD + h) * 128 + rv)) * 2048 + k0s + cv * 8], \
              &Vts[bb_][c * 64 + w * 16][0]);                                  \
    }                                                                          \
  }

  STAGE(0, 0);
  __syncthreads();
  int cur = 0;
  for (int kt = 0; kt < ktn; ++kt) {
    int k0 = kt * 32;
    if (kt + 1 < ktn) STAGE(kt + 1, cur ^ 1);  // prefetch hides under compute
    bool active = (k0 <= wave_qmax);
    if (active) {
      // QK^T: D[q][key], q=hi*4+reg (A-side), key=l15 (+16)
      f32x4 sf0 = (f32x4){0.f, 0.f, 0.f, 0.f};
      f32x4 sf1 = (f32x4){0.f, 0.f, 0.f, 0.f};
#pragma unroll
      for (int ks = 0; ks < 4; ++ks) {
        int ch = ((hi + ks * 4) ^ (l15 & 7)) * 8;  // swizzled chunk
        bf16x8 kf0 = *(const bf16x8*)&Ks[cur][l15][ch];
        bf16x8 kf1 = *(const bf16x8*)&Ks[cur][16 + l15][ch];
        sf0 = __builtin_amdgcn_mfma_f32_16x16x32_bf16(qf[ks], kf0, sf0, 0, 0, 0);
        sf1 = __builtin_amdgcn_mfma_f32_16x16x32_bf16(qf[ks], kf1, sf1, 0, 0, 0);
      }
      int kbase = k0 + l15;
#pragma unroll
      for (int reg = 0; reg < 4; ++reg) {
        int ql = hi * 4 + reg;
        int gq = qbase + ql;
        bool v0 = (kbase <= gq) && (kbase <= SCTX - 1);
        bool v1 = (kbase + 16 <= gq) && (kbase + 16 <= SCTX - 1);
        float s0 = sf0[reg] * SCALE;
        float s1 = sf1[reg] * SCALE;
        float mx = fmaxf(v0 ? s0 : -3e38f, v1 ? s1 : -3e38f);
#pragma unroll
        for (int off = 1; off < 16; off <<= 1)
          mx = fmaxf(mx, __shfl_xor(mx, off));
        float mo = m_r[reg];
        float mn = fmaxf(mo, mx);
        float cf = __expf(mo - mn);
        float p0 = v0 ? __expf(s0 - mn) : 0.f;
        float p1 = v1 ? __expf(s1 - mn) : 0.f;
        float rs = p0 + p1;
#pragma unroll
        for (int off = 1; off < 16; off <<= 1) rs += __shfl_xor(rs, off);
        l_r[reg] = l_r[reg] * cf + rs;
        m_r[reg] = mn;
#pragma unroll
        for (int df = 0; df < 8; ++df) of[df][reg] *= cf;
        Ps[w][ql][l15] = f2b(p0);
        Ps[w][ql][16 + l15] = f2b(p1);
      }
      // PV: A=P[q=l15][key=hi*8+j], B=Vt[d][key] -> D[q][d]  (wave-local P)
      bf16x8 pa = *(const bf16x8*)&Ps[w][l15][hi * 8];
#pragma unroll
      for (int df = 0; df < 8; ++df) {
        int d = df * 16 + l15;
        bf16x8 vb = *(const bf16x8*)&Vts[cur][d][(hi ^ ((d >> 1) & 3)) * 8];
        of[df] = __builtin_amdgcn_mfma_f32_16x16x32_bf16(pa, vb, of[df], 0, 0, 0);
      }
    }
    __syncthreads();  // staged tile landed + all waves done with cur
    cur ^= 1;
  }
#undef STAGE

  // epilogue: D[q][d]: q=hi*4+reg, d=l15+16*df
#pragma unroll
  for (int reg = 0; reg < 4; ++reg) {
    int gq = qbase + hi * 4 + reg;
    if (gq < S_TOT) {
      float inv = 1.0f / l_r[reg];
      ushort* orow = &attb[(long)(b * S_TOT + gq) * 512 + h * 128 + l15];
#pragma unroll
      for (int df = 0; df < 8; ++df) orow[df * 16] = f2b(of[df][reg] * inv);
    }
  }
}

// ---------------------------------------------------------------- layernorm
// One WAVE per row (4 rows/block): no LDS, no barriers, pure shfl reduce.
// x[row] = LN(x[row] + add[row]) * g + b (in-place on x) + bf16 copy.
__global__ __launch_bounds__(256) void ln_kernel(
    float* __restrict__ x, const float* __restrict__ add,
    const float* __restrict__ g, const float* __restrict__ bta,
    ushort* __restrict__ xb) {
  int row = blockIdx.x * 4 + (threadIdx.x >> 6);  // grid 4100*4 = 16400 exact
  int lane = threadIdx.x & 63;
  long base = (long)row * 512;
  int c0 = lane * 4, c1 = 256 + lane * 4;
  float4 a0 = *(const float4*)&x[base + c0];
  float4 b0 = *(const float4*)&add[base + c0];
  float4 a1 = *(const float4*)&x[base + c1];
  float4 b1 = *(const float4*)&add[base + c1];
  float v[8] = {a0.x + b0.x, a0.y + b0.y, a0.z + b0.z, a0.w + b0.w,
                a1.x + b1.x, a1.y + b1.y, a1.z + b1.z, a1.w + b1.w};
  float s = 0.f, s2 = 0.f;
#pragma unroll
  for (int j = 0; j < 8; ++j) { s += v[j]; s2 += v[j] * v[j]; }
#pragma unroll
  for (int off = 1; off < 64; off <<= 1) {
    s += __shfl_xor(s, off);
    s2 += __shfl_xor(s2, off);
  }
  float mean = s * (1.f / 512.f);
  float var = s2 * (1.f / 512.f) - mean * mean;
  float inv = 1.0f / sqrtf(var + LN_EPS);
  float4 g0 = *(const float4*)&g[c0], g1 = *(const float4*)&g[c1];
  float4 t0 = *(const float4*)&bta[c0], t1 = *(const float4*)&bta[c1];
  float o[8];
  o[0] = (v[0] - mean) * inv * g0.x + t0.x;
  o[1] = (v[1] - mean) * inv * g0.y + t0.y;
  o[2] = (v[2] - mean) * inv * g0.z + t0.z;
  o[3] = (v[3] - mean) * inv * g0.w + t0.w;
  o[4] = (v[4] - mean) * inv * g1.x + t1.x;
  o[5] = (v[5] - mean) * inv * g1.y + t1.y;
  o[6] = (v[6] - mean) * inv * g1.z + t1.z;
  o[7] = (v[7] - mean) * inv * g1.w + t1.w;
  *(float4*)&x[base + c0] = make_float4(o[0], o[1], o[2], o[3]);
  *(float4*)&x[base + c1] = make_float4(o[4], o[5], o[6], o[7]);
  ushort4 u0, u1;
  u0.x = f2b(o[0]); u0.y = f2b(o[1]); u0.z = f2b(o[2]); u0.w = f2b(o[3]);
  u1.x = f2b(o[4]); u1.y = f2b(o[5]); u1.z = f2b(o[6]); u1.w = f2b(o[7]);
  *(ushort4*)&xb[base + c0] = u0;
  *(ushort4*)&xb[base + c1] = u1;
}

// ---------------------------------------------------------------- heads
__global__ __launch_bounds__(256) void head_cat_kernel(
    const float* __restrict__ x, const float* __restrict__ w_cat,
    float* __restrict__ out0) {
  __shared__ alignas(16) float Pc[16][260];
  __shared__ alignas(16) float Ws[16][260];
  int tid = threadIdx.x;
#pragma unroll
  for (int r = 0; r < 4; ++r) {
    int e = tid + r * 256;
    int rr = e >> 6, d4 = e & 63;
    int b = rr >> 1, p = rr & 1;
    *(float4*)&Pc[rr][d4 * 4] =
        *(const float4*)&x[((long)(b * S_TOT + SCTX + p)) * 512 + d4 * 4];
  }
  int n0 = blockIdx.x * 256;
  for (int nc = 0; nc < 256; nc += 16) {
    __syncthreads();
#pragma unroll
    for (int r = 0; r < 4; ++r) {
      int e = tid + r * 256;
      int rr = e >> 6, d4 = e & 63;
      int n = n0 + nc + rr;
      float4 w = make_float4(0.f, 0.f, 0.f, 0.f);
      if (n < 50000) w = *(const float4*)&w_cat[(long)n * 256 + d4 * 4];
      *(float4*)&Ws[rr][d4 * 4] = w;
    }
    __syncthreads();
    int rr = tid >> 4, nn = tid & 15;
    float sum = 0.f;
#pragma unroll 8
    for (int d4 = 0; d4 < 64; ++d4) {
      float4 a = *(const float4*)&Pc[rr][d4 * 4];
      float4 w = *(const float4*)&Ws[nn][d4 * 4];
      sum += a.x * w.x + a.y * w.y + a.z * w.z + a.w * w.w;
    }
    int n = n0 + nc + nn;
    int b = rr >> 1, p = rr & 1;
    if (n < 50000) out0[((long)(b * 2 + p)) * 50000 + n] = sum;
  }
}

__global__ __launch_bounds__(256) void head_cont_kernel(
    const float* __restrict__ x, float* __restrict__ out1,
    float* __restrict__ out2) {
  __shared__ alignas(16) float Pt[16][132];
  __shared__ alignas(16) float Pf[16][132];
  __shared__ alignas(16) float Ws[16][132];
  int tid = threadIdx.x;
#pragma unroll
  for (int r = 0; r < 2; ++r) {
    int e = tid + r * 256;
    int rr = e >> 5, d4 = e & 31;
    int b = rr >> 1, p = rr & 1;
    long base = ((long)(b * S_TOT + SCTX + p)) * 512;
    *(float4*)&Pt[rr][d4 * 4] = *(const float4*)&x[base + 256 + d4 * 4];
    *(float4*)&Pf[rr][d4 * 4] = *(const float4*)&x[base + 384 + d4 * 4];
  }
  int n0 = blockIdx.x * 256;
  for (int nc = 0; nc < 256; nc += 16) {
    __syncthreads();
#pragma unroll
    for (int r = 0; r < 8; ++r) {
      int e = tid + r * 256;
      int rr = e >> 7, i = e & 127;
      int n = n0 + nc + rr;
      float freq = expf(-(float)i * (6.907755278982137f / 128.f));  // 1000^(-i/128)
      float ang = (float)n * freq;
      Ws[rr][i] = (i & 1) ? cosf(ang) : sinf(ang);
    }
    __syncthreads();
    int rr = tid >> 4, nn = tid & 15;
    float s1 = 0.f, s2 = 0.f;
#pragma unroll 8
    for (int d4 = 0; d4 < 32; ++d4) {
      float4 w = *(const float4*)&Ws[nn][d4 * 4];
      float4 a = *(const float4*)&Pt[rr][d4 * 4];
      float4 c = *(const float4*)&Pf[rr][d4 * 4];
      s1 += a.x * w.x + a.y * w.y + a.z * w.z + a.w * w.w;
      s2 += c.x * w.x + c.y * w.y + c.z * w.z + c.w * w.w;
    }
    int n = n0 + nc + nn;
    int b = rr >> 1, p = rr & 1;
    out1[((long)(b * 2 + p)) * 4096 + n] = s1;
    out2[((long)(b * 2 + p)) * 4096 + n] = s2;
  }
}

// ---------------------------------------------------------------- launch
extern "C" void kernel_launch(void* const* d_in, const int* in_sizes, int n_in,
                              void* d_out, int out_size, void* d_ws,
                              size_t ws_size, hipStream_t stream) {
  const int* cat = (const int*)d_in[0];
  const int* timev = (const int*)d_in[1];
  const int* f0 = (const int*)d_in[2];
  const float* w_cat = (const float*)d_in[3];
  const float* pad_emb = (const float*)d_in[4];
  const float* attn_in_w = (const float*)d_in[5];
  const float* attn_in_b = (const float*)d_in[6];
  const float* attn_out_w = (const float*)d_in[7];
  const float* attn_out_b = (const float*)d_in[8];
  const float* ff1_w = (const float*)d_in[9];
  const float* ff1_b = (const float*)d_in[10];
  const float* ff2_w = (const float*)d_in[11];
  const float* ff2_b = (const float*)d_in[12];
  const float* ln1_g = (const float*)d_in[13];
  const float* ln1_b = (const float*)d_in[14];
  const float* ln2_g = (const float*)d_in[15];
  const float* ln2_b = (const float*)d_in[16];

  // -------- workspace layout: 180.5 MB total (unchanged) --------
  const size_t REQUIRED = 180518912ull;
  if (ws_size < REQUIRED) return;

  float* X = (float*)d_ws;                           // 16400*512 f32
  float* TMP = X + (long)M_ROWS * 512;               // 16400*512 f32 (also Vt home)
  ushort* Xb = (ushort*)(TMP + (long)M_ROWS * 512);  // 16400*512 bf16
  ushort* ATTb = Xb + (long)M_ROWS * 512;            // 16400*512 bf16
  ushort* U = ATTb + (long)M_ROWS * 512;  // union: QKV(16400*1536) / HMID(16400*2048)
  ushort* Wb_ain = U + (long)M_ROWS * 2048;   // 2*1536*512
  ushort* Wb_aout = Wb_ain + 2 * 1536 * 512;  // 2*512*512
  ushort* Wb_ff1 = Wb_aout + 2 * 512 * 512;   // 2*2048*512
  ushort* Wb_ff2 = Wb_ff1 + 2 * 2048 * 512;   // 2*512*2048
  ushort* Vtb = (ushort*)TMP;  // Vt (16.78 MB) shares TMP: disjoint live ranges

  float* out0 = (float*)d_out;  // 8*2*50000
  float* out1 = out0 + 800000;  // 8*2*4096
  float* out2 = out1 + 65536;   // 8*2*4096

  cast_f32_bf16<<<1536, 256, 0, stream>>>(attn_in_w, Wb_ain, 2 * 1536 * 512 / 4);
  cast_f32_bf16<<<512, 256, 0, stream>>>(attn_out_w, Wb_aout, 2 * 512 * 512 / 4);
  cast_f32_bf16<<<2048, 256, 0, stream>>>(ff1_w, Wb_ff1, 2 * 2048 * 512 / 4);
  cast_f32_bf16<<<2048, 256, 0, stream>>>(ff2_w, Wb_ff2, 2 * 512 * 2048 / 4);

  embed_kernel<<<(M_ROWS * 512) / 256, 256, 0, stream>>>(cat, timev, f0, w_cat,
                                                         pad_emb, X, Xb);
  int mtiles = (M_ROWS + 127) / 128;  // 129
  for (int l = 0; l < NLAYER; ++l) {
    gemm_bf16<<<dim3(12, mtiles), 256, 0, stream>>>(
        Xb, Wb_ain + (long)l * 1536 * 512, attn_in_b + l * 1536, U, M_ROWS,
        1536, 512, 1, 0);  // QKV -> bf16 in U
    vt_kernel<<<dim3(32, NHEAD, BATCH), 256, 0, stream>>>(U, Vtb);
    attn_mfma<<<dim3(33, NHEAD, BATCH), 256, 0, stream>>>(U, Vtb, ATTb);
    gemm_bf16<<<dim3(4, mtiles), 256, 0, stream>>>(
        ATTb, Wb_aout + (long)l * 512 * 512, attn_out_b + l * 512, TMP, M_ROWS,
        512, 512, 0, 0);
    ln_kernel<<<M_ROWS / 4, 256, 0, stream>>>(X, TMP, ln1_g + l * 512,
                                              ln1_b + l * 512, Xb);
    gemm_bf16<<<dim3(16, mtiles), 256, 0, stream>>>(
        Xb, Wb_ff1 + (long)l * 2048 * 512, ff1_b + l * 2048, U, M_ROWS, 2048,
        512, 1, 1);  // HMID -> bf16 relu in U
    gemm_bf16<<<dim3(4, mtiles), 256, 0, stream>>>(
        U, Wb_ff2 + (long)l * 512 * 2048, ff2_b + l * 512, TMP, M_ROWS, 512,
        2048, 0, 0);
    ln_kernel<<<M_ROWS / 4, 256, 0, stream>>>(X, TMP, ln2_g + l * 512,
                                              ln2_b + l * 512, Xb);
  }
  head_cat_kernel<<<196, 256, 0, stream>>>(X, w_cat, out0);
  head_cont_kernel<<<16, 256, 0, stream>>>(X, out1, out2);
}